// Round 1
// baseline (181233.411 us; speedup 1.0000x reference)
//
#include <hip/hip_runtime.h>
#include <hip/hip_cooperative_groups.h>
#include <math.h>

namespace cg = cooperative_groups;

#define Z_DIM   256
#define HID     1024
#define VOCAB   512
#define SEQ_LEN 512
#define BATCH   64
#define NBLK    256
#define NTHR    256

// ws layout (float offsets)
#define WS_EXPT   0          // [VOCAB][BATCH] exp(logit - max), 32768
#define WS_RCPS   32768      // [BATCH] 1/sum(exp)
#define WS_H0A    32832      // [HID][BATCH]
#define WS_H0B    98368
#define WS_H1A    163904
#define WS_H1B    229440
#define WS_C0     294976
#define WS_C1     360512
#define WS_B0     426048     // [4*HID] combined bias layer0
#define WS_B1     430144
#define WS_OWT    434240     // out_w transposed [HID][VOCAB], 524288

__device__ __forceinline__ float sigm(float x) { return 1.f / (1.f + expf(-x)); }

// 4-gate dot: rows (g*HID + ju) of w (row length K) against activation column
// actc[k*64] (lane-strided transposed activations). Weights are wave-uniform.
__device__ __forceinline__ void gate_dot(const float* __restrict__ w, int ju, int K,
                                         const float* __restrict__ actc,
                                         float& gi, float& gf, float& gg, float& go)
{
    const float4* wi = (const float4*)(w + (size_t)ju * K);
    const float4* wf = (const float4*)(w + ((size_t)HID + ju) * K);
    const float4* wg = (const float4*)(w + ((size_t)(2 * HID) + ju) * K);
    const float4* wo = (const float4*)(w + ((size_t)(3 * HID) + ju) * K);
#pragma unroll 2
    for (int k4 = 0; k4 < (K >> 2); ++k4) {
        const float4 a = wi[k4];
        const float4 b = wf[k4];
        const float4 c = wg[k4];
        const float4 d = wo[k4];
        const int kb = k4 << 8;
        const float x0 = actc[kb];
        const float x1 = actc[kb + 64];
        const float x2 = actc[kb + 128];
        const float x3 = actc[kb + 192];
        gi = fmaf(a.x, x0, fmaf(a.y, x1, fmaf(a.z, x2, fmaf(a.w, x3, gi))));
        gf = fmaf(b.x, x0, fmaf(b.y, x1, fmaf(b.z, x2, fmaf(b.w, x3, gf))));
        gg = fmaf(c.x, x0, fmaf(c.y, x1, fmaf(c.z, x2, fmaf(c.w, x3, gg))));
        go = fmaf(d.x, x0, fmaf(d.y, x1, fmaf(d.z, x2, fmaf(d.w, x3, go))));
    }
}

__global__ __launch_bounds__(NTHR) void lstm_persistent(
    const float* __restrict__ z,     const float* __restrict__ fc_w,
    const float* __restrict__ fc_b,  const float* __restrict__ w_ih0,
    const float* __restrict__ w_hh0, const float* __restrict__ b_ih0,
    const float* __restrict__ b_hh0, const float* __restrict__ w_ih1,
    const float* __restrict__ w_hh1, const float* __restrict__ b_ih1,
    const float* __restrict__ b_hh1, const float* __restrict__ out_w,
    const float* __restrict__ out_b, float* __restrict__ out,
    float* __restrict__ ws)
{
    cg::grid_group grid = cg::this_grid();
    const int tid   = threadIdx.x;
    const int lane  = tid & 63;
    const int widx  = tid >> 6;
    const int gwave = blockIdx.x * (NTHR / 64) + widx;   // 0..1023
    const int ju    = __builtin_amdgcn_readfirstlane(gwave);

    float* expT = ws + WS_EXPT;
    float* rcpS = ws + WS_RCPS;
    float* h0A  = ws + WS_H0A;
    float* h0B  = ws + WS_H0B;
    float* h1A  = ws + WS_H1A;
    float* h1B  = ws + WS_H1B;
    float* c0T  = ws + WS_C0;
    float* c1T  = ws + WS_C1;
    float* b0   = ws + WS_B0;
    float* b1   = ws + WS_B1;
    float* owT  = ws + WS_OWT;

    __shared__ float sred[8];

    // ---------------- init ----------------
    {
        const int gtid = blockIdx.x * NTHR + tid;
        if (gtid < 4096)        b0[gtid] = b_ih0[gtid] + b_hh0[gtid];
        else if (gtid < 8192) { const int n = gtid - 4096; b1[n] = b_ih1[n] + b_hh1[n]; }
        if (gtid < 32768) expT[gtid] = 0.f;
        if (gtid < 64)    rcpS[gtid] = 1.f;
        // transpose out_w [VOCAB][HID] -> owT [HID][VOCAB] (coalesced writes)
#pragma unroll
        for (int r = 0; r < 8; ++r) {
            const int idx = gtid + r * 65536;       // idx = k*512 + v
            const int v = idx & 511;
            const int k = idx >> 9;
            owT[idx] = out_w[(size_t)v * HID + k];
        }
        // h_init = tanh(z @ fc_w.T + fc_b); wave ju, lane = batch
        {
            const float4* wr = (const float4*)(fc_w + (size_t)ju * Z_DIM);
            const float4* zr = (const float4*)(z + (size_t)lane * Z_DIM);
            float acc = 0.f;
#pragma unroll 4
            for (int k4 = 0; k4 < Z_DIM / 4; ++k4) {
                const float4 a = wr[k4];
                const float4 x = zr[k4];
                acc = fmaf(a.x, x.x, fmaf(a.y, x.y, fmaf(a.z, x.z, fmaf(a.w, x.w, acc))));
            }
            const float h = tanhf(acc + fc_b[ju]);
            const int ci = (ju << 6) + lane;
            h0A[ci] = h;
            h1A[ci] = h;
            c0T[ci] = 0.f;
            c1T[ci] = 0.f;
        }
    }
    grid.sync();

    for (int t = 0; t < SEQ_LEN; ++t) {
        const int par = t & 1;
        const float* h0_r = par ? h0B : h0A;
        float*       h0_w = par ? h0A : h0B;
        const float* h1_r = par ? h1B : h1A;
        float*       h1_w = par ? h1A : h1B;

        // ---------------- P0: layer0 cell ----------------
        {
            float xi = 0.f, xf = 0.f, xg = 0.f, xo = 0.f;
            gate_dot(w_ih0, ju, VOCAB, expT + lane, xi, xf, xg, xo);
            const float rs = rcpS[lane];
            float gi = fmaf(xi, rs, b0[ju]);
            float gf = fmaf(xf, rs, b0[HID + ju]);
            float gg = fmaf(xg, rs, b0[2 * HID + ju]);
            float go = fmaf(xo, rs, b0[3 * HID + ju]);
            gate_dot(w_hh0, ju, HID, h0_r + lane, gi, gf, gg, go);
            const float i_ = sigm(gi), f_ = sigm(gf), g_ = tanhf(gg), o_ = sigm(go);
            const int ci = (ju << 6) + lane;
            const float cn = fmaf(f_, c0T[ci], i_ * g_);
            c0T[ci]  = cn;
            h0_w[ci] = o_ * tanhf(cn);
        }
        grid.sync();

        // ---------------- P1: layer1 cell ----------------
        {
            float gi = b1[ju];
            float gf = b1[HID + ju];
            float gg = b1[2 * HID + ju];
            float go = b1[3 * HID + ju];
            gate_dot(w_ih1, ju, HID, h0_w + lane, gi, gf, gg, go);
            gate_dot(w_hh1, ju, HID, h1_r + lane, gi, gf, gg, go);
            const float i_ = sigm(gi), f_ = sigm(gf), g_ = tanhf(gg), o_ = sigm(go);
            const int ci = (ju << 6) + lane;
            const float cn = fmaf(f_, c1T[ci], i_ * g_);
            c1T[ci]  = cn;
            h1_w[ci] = o_ * tanhf(cn);
        }
        grid.sync();

        // ---------------- P2: logits + softmax prep (one block per batch) ----
        if (blockIdx.x < BATCH) {
            const int b = blockIdx.x;
            const int v = tid;                       // 0..255; handles v and v+256
            const float* hb = h1_w + b;              // h1_new[k][b], wave-uniform
            const float* w0 = owT + v;
            const float* w1 = owT + v + 256;
            float l0 = 0.f, l1 = 0.f;
#pragma unroll 4
            for (int k = 0; k < HID; ++k) {
                const float hv = hb[k << 6];
                l0 = fmaf(w0[(size_t)k << 9], hv, l0);
                l1 = fmaf(w1[(size_t)k << 9], hv, l1);
            }
            l0 += out_b[v];
            l1 += out_b[v + 256];
            const size_t obase = ((size_t)b * SEQ_LEN + t) * VOCAB;
            out[obase + v]       = l0;
            out[obase + v + 256] = l1;
            // block softmax over 512 logits
            float m = fmaxf(l0, l1);
#pragma unroll
            for (int off = 32; off; off >>= 1) m = fmaxf(m, __shfl_xor(m, off));
            if (lane == 0) sred[widx] = m;
            __syncthreads();
            const float M = fmaxf(fmaxf(sred[0], sred[1]), fmaxf(sred[2], sred[3]));
            const float e0 = expf(l0 - M);
            const float e1 = expf(l1 - M);
            float s = e0 + e1;
#pragma unroll
            for (int off = 32; off; off >>= 1) s += __shfl_xor(s, off);
            if (lane == 0) sred[4 + widx] = s;
            __syncthreads();
            expT[(v << 6) + b]         = e0;
            expT[((v + 256) << 6) + b] = e1;
            if (tid == 0) rcpS[b] = 1.f / (sred[4] + sred[5] + sred[6] + sred[7]);
        }
        grid.sync();
    }
}

extern "C" void kernel_launch(void* const* d_in, const int* in_sizes, int n_in,
                              void* d_out, int out_size, void* d_ws, size_t ws_size,
                              hipStream_t stream) {
    const float* z     = (const float*)d_in[0];
    const float* fc_w  = (const float*)d_in[1];
    const float* fc_b  = (const float*)d_in[2];
    const float* w_ih0 = (const float*)d_in[3];
    const float* w_hh0 = (const float*)d_in[4];
    const float* b_ih0 = (const float*)d_in[5];
    const float* b_hh0 = (const float*)d_in[6];
    const float* w_ih1 = (const float*)d_in[7];
    const float* w_hh1 = (const float*)d_in[8];
    const float* b_ih1 = (const float*)d_in[9];
    const float* b_hh1 = (const float*)d_in[10];
    const float* out_w = (const float*)d_in[11];
    const float* out_b = (const float*)d_in[12];
    float* out = (float*)d_out;
    float* ws  = (float*)d_ws;

    void* args[] = { &z, &fc_w, &fc_b, &w_ih0, &w_hh0, &b_ih0, &b_hh0,
                     &w_ih1, &w_hh1, &b_ih1, &b_hh1, &out_w, &out_b, &out, &ws };
    hipLaunchCooperativeKernel((const void*)lstm_persistent,
                               dim3(NBLK), dim3(NTHR), args, 0, stream);
}

// Round 3
// 116921.851 us; speedup vs baseline: 1.5500x; 1.5500x over previous
//
#include <hip/hip_runtime.h>
#include <hip/hip_cooperative_groups.h>
#include <math.h>

namespace cg = cooperative_groups;

#define Z_DIM   256
#define HID     1024
#define VOCAB   512
#define SEQ_LEN 512
#define BATCH   64
#define NBLK    256
#define NTHR    256
#define CHUNK   128

// ws layout (float offsets) — all 16B-aligned
#define WS_EXPT   0          // [VOCAB][64] exp(logit - max), UNNORMALIZED
#define WS_RCPS   32768      // [64] 1/sum(exp)
#define WS_H0A    32832      // [HID][64]
#define WS_H0B    98368
#define WS_H1A    163904
#define WS_H1B    229440
#define WS_C0     294976
#define WS_C1     360512
#define WS_B0     426048     // [4*HID]
#define WS_B1     430144     // [4*HID]

__device__ __forceinline__ float sigm(float x) { return 1.f / (1.f + expf(-x)); }

// One gate-GEMM segment: accumulate gates (i,f,g,o) for unit ju over K, acts
// src in [K][64] layout. Single-LDS-buffer pipeline, register prefetch.
// FMA order matches round-1's gate_dot exactly (k ascending quads, nested fma).
__device__ __forceinline__ void phaseK(
    const float* __restrict__ w, int K,           // gate rows [4*HID][K]
    const float* __restrict__ src, int nc,        // acts [K][64], nc = K/128
    int ju, int widx, int lane, int tid,
    float* __restrict__ sA, float* __restrict__ sW,
    float& gi, float& gf, float& gg, float& go)
{
    const int r  = lane >> 4;             // gate this lane stages
    const int wc = (lane & 15) << 3;      // weight col (8 floats/lane)
    float4 a0, a1, a2, a3, a4, a5, a6, a7, vw0, vw1;

    auto pre = [&](int c) {               // global -> regs (private, no LDS)
        const float4* g4 = (const float4*)(src + (size_t)(c * CHUNK) * 64);
        a0 = g4[tid];        a1 = g4[tid + 256];
        a2 = g4[tid + 512];  a3 = g4[tid + 768];
        a4 = g4[tid + 1024]; a5 = g4[tid + 1280];
        a6 = g4[tid + 1536]; a7 = g4[tid + 1792];
        const float* wp = w + (size_t)(r * HID + ju) * K + c * CHUNK + wc;
        vw0 = *(const float4*)wp;
        vw1 = *(const float4*)(wp + 4);
    };

    pre(0);
    for (int c = 0; c < nc; ++c) {
        __syncthreads();                  // (A) everyone done reading LDS
        {                                 // regs -> LDS (identity layout)
            float4* dA = (float4*)sA;
            dA[tid]        = a0; dA[tid + 256]  = a1;
            dA[tid + 512]  = a2; dA[tid + 768]  = a3;
            dA[tid + 1024] = a4; dA[tid + 1280] = a5;
            dA[tid + 1536] = a6; dA[tid + 1792] = a7;
            float* wd = sW + (widx * 4 + r) * CHUNK + wc;
            *(float4*)wd       = vw0;
            *(float4*)(wd + 4) = vw1;
        }
        __syncthreads();                  // (B) LDS visible
        if (c + 1 < nc) pre(c + 1);       // prefetch; latency hides under comp
        const float* As = sA + lane;
        const float* Wr = sW + widx * 4 * CHUNK;
#pragma unroll
        for (int q = 0; q < CHUNK / 4; ++q) {
            const float4 wi = *(const float4*)&Wr[4 * q];                // uniform
            const float4 wf = *(const float4*)&Wr[CHUNK + 4 * q];
            const float4 wg = *(const float4*)&Wr[2 * CHUNK + 4 * q];
            const float4 wo = *(const float4*)&Wr[3 * CHUNK + 4 * q];
            const float x0 = As[(q << 8)];
            const float x1 = As[(q << 8) + 64];
            const float x2 = As[(q << 8) + 128];
            const float x3 = As[(q << 8) + 192];
            gi = fmaf(wi.x, x0, fmaf(wi.y, x1, fmaf(wi.z, x2, fmaf(wi.w, x3, gi))));
            gf = fmaf(wf.x, x0, fmaf(wf.y, x1, fmaf(wf.z, x2, fmaf(wf.w, x3, gf))));
            gg = fmaf(wg.x, x0, fmaf(wg.y, x1, fmaf(wg.z, x2, fmaf(wg.w, x3, gg))));
            go = fmaf(wo.x, x0, fmaf(wo.y, x1, fmaf(wo.z, x2, fmaf(wo.w, x3, go))));
        }
    }
}

__global__ __launch_bounds__(NTHR) void lstm_persistent(
    const float* __restrict__ z,     const float* __restrict__ fc_w,
    const float* __restrict__ fc_b,  const float* __restrict__ w_ih0,
    const float* __restrict__ w_hh0, const float* __restrict__ b_ih0,
    const float* __restrict__ b_hh0, const float* __restrict__ w_ih1,
    const float* __restrict__ w_hh1, const float* __restrict__ b_ih1,
    const float* __restrict__ b_hh1, const float* __restrict__ out_w,
    const float* __restrict__ out_b, float* __restrict__ out,
    float* __restrict__ ws)
{
    cg::grid_group grid = cg::this_grid();
    const int tid  = threadIdx.x;
    const int lane = tid & 63;
    const int widx = tid >> 6;
    const int ju   = blockIdx.x * 4 + widx;      // hidden unit 0..1023

    float* expT = ws + WS_EXPT;
    float* rcpS = ws + WS_RCPS;
    float* h0A  = ws + WS_H0A;
    float* h0B  = ws + WS_H0B;
    float* h1A  = ws + WS_H1A;
    float* h1B  = ws + WS_H1B;
    float* c0T  = ws + WS_C0;
    float* c1T  = ws + WS_C1;
    float* b0   = ws + WS_B0;
    float* b1   = ws + WS_B1;

    __shared__ float sA[64 * CHUNK];     // acts [k][64], single buffer
    __shared__ float sW[16 * CHUNK];     // weights: 4 waves x 4 gate rows
    __shared__ float h1s[HID];
    __shared__ float sred[8];

    // ---------------- init ----------------
    {
        const int gtid = blockIdx.x * NTHR + tid;
        if (gtid < 4096)        b0[gtid] = b_ih0[gtid] + b_hh0[gtid];
        else if (gtid < 8192) { const int n = gtid - 4096; b1[n] = b_ih1[n] + b_hh1[n]; }
        if (gtid < 32768) expT[gtid] = 0.f;
        if (gtid < 64)    rcpS[gtid] = 1.f;
        const float4* wr = (const float4*)(fc_w + (size_t)ju * Z_DIM);
        const float4* zr = (const float4*)(z + (size_t)lane * Z_DIM);
        float acc = 0.f;
#pragma unroll 4
        for (int k4 = 0; k4 < Z_DIM / 4; ++k4) {
            const float4 a = wr[k4];
            const float4 x = zr[k4];
            acc = fmaf(a.x, x.x, fmaf(a.y, x.y, fmaf(a.z, x.z, fmaf(a.w, x.w, acc))));
        }
        const float h = tanhf(acc + fc_b[ju]);
        const int ci = (ju << 6) + lane;
        h0A[ci] = h;
        h1A[ci] = h;
        c0T[ci] = 0.f;
        c1T[ci] = 0.f;
    }
    grid.sync();

    for (int t = 0; t < SEQ_LEN; ++t) {
        const int par = t & 1;
        const float* h0_r = par ? h0B : h0A;
        float*       h0_w = par ? h0A : h0B;
        const float* h1_r = par ? h1B : h1A;
        float*       h1_w = par ? h1A : h1B;

        // ---------------- P0: layer0 gates + cell ----------------
        {
            float xi = 0.f, xf = 0.f, xg = 0.f, xo = 0.f;
            phaseK(w_ih0, VOCAB, expT, 4, ju, widx, lane, tid, sA, sW, xi, xf, xg, xo);
            const float rs = rcpS[lane];
            float gi = fmaf(xi, rs, b0[ju]);
            float gf = fmaf(xf, rs, b0[HID + ju]);
            float gg = fmaf(xg, rs, b0[2 * HID + ju]);
            float go = fmaf(xo, rs, b0[3 * HID + ju]);
            phaseK(w_hh0, HID, h0_r, 8, ju, widx, lane, tid, sA, sW, gi, gf, gg, go);
            const float i_ = sigm(gi), f_ = sigm(gf), g_ = tanhf(gg), o_ = sigm(go);
            const int ci = (ju << 6) + lane;
            const float cn = fmaf(f_, c0T[ci], i_ * g_);
            c0T[ci]  = cn;
            h0_w[ci] = o_ * tanhf(cn);
        }
        grid.sync();

        // ---------------- P1: layer1 gates + cell ----------------
        {
            float gi = b1[ju], gf = b1[HID + ju], gg = b1[2 * HID + ju], go = b1[3 * HID + ju];
            phaseK(w_ih1, HID, h0_w, 8, ju, widx, lane, tid, sA, sW, gi, gf, gg, go);
            phaseK(w_hh1, HID, h1_r, 8, ju, widx, lane, tid, sA, sW, gi, gf, gg, go);
            const float i_ = sigm(gi), f_ = sigm(gf), g_ = tanhf(gg), o_ = sigm(go);
            const int ci = (ju << 6) + lane;
            const float cn = fmaf(f_, c1T[ci], i_ * g_);
            c1T[ci]  = cn;
            h1_w[ci] = o_ * tanhf(cn);
        }
        grid.sync();

        // ---------------- P2: logits + softmax (block b = batch) ----------------
        if (blockIdx.x < BATCH) {
            const int b = blockIdx.x;
#pragma unroll
            for (int i = 0; i < 4; ++i) {
                const int k = tid + i * 256;
                h1s[k] = h1_w[(size_t)k * 64 + b];
            }
            __syncthreads();
            const int v0 = tid, v1 = tid + 256;
            float l0 = 0.f, l1 = 0.f;
            const float4* r0 = (const float4*)(out_w + (size_t)v0 * HID);
            const float4* r1 = (const float4*)(out_w + (size_t)v1 * HID);
#pragma unroll 4
            for (int k4 = 0; k4 < HID / 4; ++k4) {
                const float4 h = *(const float4*)&h1s[k4 << 2];   // uniform broadcast
                const float4 a0 = r0[k4];
                const float4 a1 = r1[k4];
                l0 = fmaf(a0.x, h.x, l0); l1 = fmaf(a1.x, h.x, l1);
                l0 = fmaf(a0.y, h.y, l0); l1 = fmaf(a1.y, h.y, l1);
                l0 = fmaf(a0.z, h.z, l0); l1 = fmaf(a1.z, h.z, l1);
                l0 = fmaf(a0.w, h.w, l0); l1 = fmaf(a1.w, h.w, l1);
            }
            l0 += out_b[v0];
            l1 += out_b[v1];
            const size_t obase = ((size_t)b * SEQ_LEN + t) * VOCAB;
            out[obase + v0] = l0;
            out[obase + v1] = l1;
            float m = fmaxf(l0, l1);
#pragma unroll
            for (int off = 32; off; off >>= 1) m = fmaxf(m, __shfl_xor(m, off));
            if (lane == 0) sred[widx] = m;
            __syncthreads();
            const float M = fmaxf(fmaxf(sred[0], sred[1]), fmaxf(sred[2], sred[3]));
            const float e0 = expf(l0 - M);
            const float e1 = expf(l1 - M);
            float s = e0 + e1;
#pragma unroll
            for (int off = 32; off; off >>= 1) s += __shfl_xor(s, off);
            if (lane == 0) sred[4 + widx] = s;
            __syncthreads();
            expT[(size_t)v0 * 64 + b] = e0;          // unnormalized (round-1 exact)
            expT[(size_t)v1 * 64 + b] = e1;
            if (tid == 0) rcpS[b] = 1.f / (sred[4] + sred[5] + sred[6] + sred[7]);
        }
        grid.sync();
    }
}

extern "C" void kernel_launch(void* const* d_in, const int* in_sizes, int n_in,
                              void* d_out, int out_size, void* d_ws, size_t ws_size,
                              hipStream_t stream) {
    const float* z     = (const float*)d_in[0];
    const float* fc_w  = (const float*)d_in[1];
    const float* fc_b  = (const float*)d_in[2];
    const float* w_ih0 = (const float*)d_in[3];
    const float* w_hh0 = (const float*)d_in[4];
    const float* b_ih0 = (const float*)d_in[5];
    const float* b_hh0 = (const float*)d_in[6];
    const float* w_ih1 = (const float*)d_in[7];
    const float* w_hh1 = (const float*)d_in[8];
    const float* b_ih1 = (const float*)d_in[9];
    const float* b_hh1 = (const float*)d_in[10];
    const float* out_w = (const float*)d_in[11];
    const float* out_b = (const float*)d_in[12];
    float* out = (float*)d_out;
    float* ws  = (float*)d_ws;

    void* args[] = { &z, &fc_w, &fc_b, &w_ih0, &w_hh0, &b_ih0, &b_hh0,
                     &w_ih1, &w_hh1, &b_ih1, &b_hh1, &out_w, &out_b, &out, &ws };
    hipLaunchCooperativeKernel((const void*)lstm_persistent,
                               dim3(NBLK), dim3(NTHR), args, 0, stream);
}